// Round 7
// baseline (45.558 us; speedup 1.0000x reference)
//
#include <hip/hip_runtime.h>

#define B_SZ   512
#define IN_F   256
#define OUT_F  256
#define NINT   15
#define IQ     64             // input features per block (IN-dim split in 4)
#define NC4    (IQ * NINT)    // float4 coeff entries per block = 960

typedef const __attribute__((address_space(1))) void gvoid_t;
typedef __attribute__((address_space(3))) void lvoid_t;

__device__ __forceinline__ float kan_eval(float wv, float xv,
                                          const float4* __restrict__ sc, int cbase) {
    const float kD = 2.0f / 15.0f;                 // fl32(2/15), XLA's delta bits
    float wx = wv * xv;                            // ref's exact f32 product
    float xc = fminf(fmaxf(wx, -1.0f), 1.0f);
    // down-biased floor: guess error <5e-6, bias 1e-4 => i0 ∈ {j_true-1, j_true}
    float u  = __builtin_fmaf(xc, 7.5f, 7.4999f);  // u ∈ [-1e-4, 14.9999] -> i0 ∈ [0,14]
    int   i0 = (int)u;
    float f0 = (float)i0;
    // exact XLA-linspace bits: separate mul/add roundings (no contraction)
    float blo = __fadd_rn(__fmul_rn(f0, kD), -1.0f);                   // bp[i0]
    float bhi = __fadd_rn(__fmul_rn(__fadd_rn(f0, 1.0f), kD), -1.0f);  // bp[i0+1]
    bool  up = (xc >= bhi);                        // exact searchsorted(right)-1
    int   j  = i0 + (up ? 1 : 0);                  // j<=14 automatic: bp[15] > 1 >= xc
    float bj = up ? bhi : blo;
    float dx = xc - bj;                            // ref's exact f32 sub
    float4 c = sc[cbase + j];
    return __builtin_fmaf(__builtin_fmaf(__builtin_fmaf(c.w, dx, c.z), dx, c.y), dx, c.x);
}

__global__ __launch_bounds__(512, 8)
void kan_kernel(const float* __restrict__ x,
                const float* __restrict__ w,
                const float* __restrict__ bias,
                const float* __restrict__ coeffs,
                float* __restrict__ out)
{
    __shared__ float4 sc[NC4];      // 15360 B -> 4 blocks/CU (wave-capped), 100% occ
    __shared__ float4 sw4[IQ / 4];  // 256 B: weights quarter-row

    // q-major: the 4 partial-blocks of one o land on the SAME XCD (256 % 8 == 0),
    // so the atomicAdd cacheline stays in one L2.
    const int o = blockIdx.x & (OUT_F - 1);  // output feature
    const int q = blockIdx.x >> 8;           // which IN-quarter
    const int b = threadIdx.x;               // batch row

    // Stage this quarter's coeffs (15360 B) global->LDS, width-16, linear dest.
    const float4* gsrc = reinterpret_cast<const float4*>(coeffs)
                         + ((size_t)o * IN_F + q * IQ) * NINT;
    #pragma unroll
    for (int k = 0; k < 2; ++k) {
        int t = b + k * 512;
        if (t < NC4) {  // k==1: b<448 = 7 whole waves — wave-uniform predicate
            __builtin_amdgcn_global_load_lds((gvoid_t*)(gsrc + t), (lvoid_t*)(sc + t), 16, 0, 0);
        }
    }
    if (b < IQ / 4) {
        sw4[b] = reinterpret_cast<const float4*>(w + (size_t)o * IN_F + q * IQ)[b];
    }
    __syncthreads();

    const float4* xrow = reinterpret_cast<const float4*>(x + (size_t)b * IN_F + q * IQ);
    float a0 = 0.f, a1 = 0.f, a2 = 0.f, a3 = 0.f;

    #pragma unroll 4
    for (int i4 = 0; i4 < IQ / 4; ++i4) {
        float4 xv = xrow[i4];
        float4 wv = sw4[i4];
        int cb = i4 * 4 * NINT;
        a0 += kan_eval(wv.x, xv.x, sc, cb);
        a1 += kan_eval(wv.y, xv.y, sc, cb + NINT);
        a2 += kan_eval(wv.z, xv.z, sc, cb + 2 * NINT);
        a3 += kan_eval(wv.w, xv.w, sc, cb + 3 * NINT);
    }

    float acc = (a0 + a1) + (a2 + a3);
    if (q == 0) acc += bias[o];
    // out zeroed by memsetAsync each launch; 4 commutative adds per element.
    atomicAdd(out + (size_t)b * OUT_F + o, acc);
}

extern "C" void kernel_launch(void* const* d_in, const int* in_sizes, int n_in,
                              void* d_out, int out_size, void* d_ws, size_t ws_size,
                              hipStream_t stream) {
    (void)d_ws; (void)ws_size;

    const float *x = nullptr, *wgt = nullptr, *bias = nullptr, *coeffs = nullptr;
    for (int i = 0; i < n_in; ++i) {
        switch (in_sizes[i]) {
            case 512 * 256:           x      = (const float*)d_in[i]; break;
            case 256 * 256:           wgt    = (const float*)d_in[i]; break;
            case 256:                 bias   = (const float*)d_in[i]; break;
            case 256 * 256 * 15 * 4:  coeffs = (const float*)d_in[i]; break;
            default: break;
        }
    }

    hipMemsetAsync(d_out, 0, (size_t)out_size * sizeof(float), stream);
    kan_kernel<<<4 * OUT_F, B_SZ, 0, stream>>>(x, wgt, bias, coeffs, (float*)d_out);
}

// Round 8
// 36.034 us; speedup vs baseline: 1.2643x; 1.2643x over previous
//
#include <hip/hip_runtime.h>

#define B_SZ   512
#define IN_F   256
#define OUT_F  256
#define NINT   15
#define IHALF  128            // input features per block (IN-dim split in 2)
#define NC4    (IHALF * NINT) // float4 coeff entries per block = 1920
#define NGRP   (IHALF / 8)    // 16 groups of 8 evals

typedef const __attribute__((address_space(1))) void gvoid_t;
typedef __attribute__((address_space(3))) void lvoid_t;

__global__ __launch_bounds__(512, 4)
void kan_kernel(const float* __restrict__ x,
                const float* __restrict__ w,
                const float* __restrict__ bias,
                const float* __restrict__ coeffs,
                float* __restrict__ out)
{
    __shared__ float4 sc[NC4];        // 30720 B -> 2 blocks/CU
    __shared__ float4 sw4[IHALF / 4]; // 512 B: weights half-row

    const int o = blockIdx.x >> 1;    // output feature
    const int h = blockIdx.x & 1;     // which IN-half
    const int b = threadIdx.x;        // batch row

    // Stage this half's coeffs (30720 B) global->LDS, width-16, linear dest.
    const float4* gsrc = reinterpret_cast<const float4*>(coeffs)
                         + ((size_t)o * IN_F + h * IHALF) * NINT;
    #pragma unroll
    for (int k = 0; k < 4; ++k) {
        int t = b + k * 512;
        if (t < NC4) {  // k==3: b<384 = 6 whole waves — wave-uniform predicate
            __builtin_amdgcn_global_load_lds((gvoid_t*)(gsrc + t), (lvoid_t*)(sc + t), 16, 0, 0);
        }
    }
    if (b < IHALF / 4) {
        sw4[b] = reinterpret_cast<const float4*>(w + (size_t)o * IN_F + h * IHALF)[b];
    }
    __syncthreads();

    const float4* xrow = reinterpret_cast<const float4*>(x + (size_t)b * IN_F + h * IHALF);
    const float kD = 2.0f / 15.0f;  // fl32(2/15), XLA's delta bits

    float acc[4] = {0.f, 0.f, 0.f, 0.f};

    // rolling x prefetch: group g's x loaded during group g-1's compute
    float4 xa = xrow[0], xb = xrow[1];

    #pragma unroll 1
    for (int g = 0; g < NGRP; ++g) {
        int gn = (g + 1) & (NGRP - 1);          // wraps to 0 on last iter (harmless reload)
        float4 xn0 = xrow[2 * gn];
        float4 xn1 = xrow[2 * gn + 1];
        float4 wa = sw4[2 * g], wb = sw4[2 * g + 1];

        float wvs[8] = {wa.x, wa.y, wa.z, wa.w, wb.x, wb.y, wb.z, wb.w};
        float xvs[8] = {xa.x, xa.y, xa.z, xa.w, xb.x, xb.y, xb.z, xb.w};

        // phase 1: 8 binnings (exact XLA-linspace semantics, see R5/R6)
        int   jj[8];
        float dxv[8];
        #pragma unroll
        for (int e = 0; e < 8; ++e) {
            float p  = wvs[e] * xvs[e];                    // ref's exact f32 product
            float xc = fminf(fmaxf(p, -1.0f), 1.0f);
            float u  = __builtin_fmaf(xc, 7.5f, 7.4999f);  // down-biased floor guess
            int   i0 = (int)u;                             // ∈ [0,14]
            float f0 = (float)i0;
            float blo = __fadd_rn(__fmul_rn(f0, kD), -1.0f);
            float bhi = __fadd_rn(__fmul_rn(__fadd_rn(f0, 1.0f), kD), -1.0f);
            bool  up = (xc >= bhi);                        // exact searchsorted(right)-1
            jj[e]  = i0 + (up ? 1 : 0);
            dxv[e] = xc - (up ? bhi : blo);                // ref's exact f32 sub
        }

        // phase 2: 8 independent gathers, batched (96 cyc issue covers ~120 cyc latency)
        float4 c[8];
        #pragma unroll
        for (int e = 0; e < 8; ++e) {
            c[e] = sc[(8 * g + e) * NINT + jj[e]];
        }

        // phase 3: 8 Horners into 4 accumulator chains
        #pragma unroll
        for (int e = 0; e < 8; ++e) {
            float y = __builtin_fmaf(__builtin_fmaf(__builtin_fmaf(
                          c[e].w, dxv[e], c[e].z), dxv[e], c[e].y), dxv[e], c[e].x);
            acc[e & 3] += y;
        }

        xa = xn0; xb = xn1;
    }

    float r = (acc[0] + acc[1]) + (acc[2] + acc[3]);
    if (h == 0) r += bias[o];
    // out zeroed by memsetAsync each launch; exactly 2 commutative adds from
    // exact 0 per element -> bitwise deterministic regardless of arrival order.
    atomicAdd(out + (size_t)b * OUT_F + o, r);
}

extern "C" void kernel_launch(void* const* d_in, const int* in_sizes, int n_in,
                              void* d_out, int out_size, void* d_ws, size_t ws_size,
                              hipStream_t stream) {
    (void)d_ws; (void)ws_size;

    const float *x = nullptr, *wgt = nullptr, *bias = nullptr, *coeffs = nullptr;
    for (int i = 0; i < n_in; ++i) {
        switch (in_sizes[i]) {
            case 512 * 256:           x      = (const float*)d_in[i]; break;
            case 256 * 256:           wgt    = (const float*)d_in[i]; break;
            case 256:                 bias   = (const float*)d_in[i]; break;
            case 256 * 256 * 15 * 4:  coeffs = (const float*)d_in[i]; break;
            default: break;
        }
    }

    hipMemsetAsync(d_out, 0, (size_t)out_size * sizeof(float), stream);
    kan_kernel<<<2 * OUT_F, B_SZ, 0, stream>>>(x, wgt, bias, coeffs, (float*)d_out);
}